// Round 4
// baseline (259.572 us; speedup 1.0000x reference)
//
#include <hip/hip_runtime.h>

// Problem constants
#define BATCH 16384
#define KEYD  64
#define DDIM  128
#define UDIM  128
#define MODES 32

typedef __attribute__((ext_vector_type(8))) short bf16x8;   // 8 bf16 in 4 VGPRs
typedef __attribute__((ext_vector_type(4))) float f32x4;

__device__ __forceinline__ unsigned short f2bf(float f) {
  unsigned u = __float_as_uint(f);
  unsigned r = (u + 0x7FFFu + ((u >> 16) & 1u)) >> 16;  // RNE bf16
  return (unsigned short)r;
}

__device__ __forceinline__ void gld_lds16(const void* g, void* l) {
  __builtin_amdgcn_global_load_lds(
      (const __attribute__((address_space(1))) unsigned int*)g,
      (__attribute__((address_space(3))) unsigned int*)l, 16, 0, 0);
}

// ---------------------------------------------------------------------------
// Fused prep (one dispatch) — unchanged proven version:
//  blocks [0,512): sim softmax (32 rows/block) + x->bf16.
//  blocks [512,770): cast kernels+biases to bf16 in MFMA-B fragment layout
//    kb16[m][kblk][u][j] = kernels[m][kblk*8+j][u] -> every B-fragment is a
//    contiguous 16B chunk (global_load_lds width-16 friendly).
// ---------------------------------------------------------------------------
__global__ __launch_bounds__(256) void prep_all(
    const float* __restrict__ key, const float* __restrict__ x,
    const float* __restrict__ sens, const float* __restrict__ keys_map,
    const float* __restrict__ kernels, const float* __restrict__ biases,
    float* __restrict__ sim, unsigned short* __restrict__ x16,
    unsigned short* __restrict__ kb16, unsigned short* __restrict__ bb16) {
  const int t = threadIdx.x;
  const int bid = blockIdx.x;

  if (bid < BATCH / 32) {
    __shared__ float kr[32][KEYD];  // 32 key rows, 8KB
    *(float4*)(&kr[0][0] + t * 4) =
        *(const float4*)(key + (long)bid * 32 * KEYD + t * 4);
    *(float4*)(&kr[0][0] + 1024 + t * 4) =
        *(const float4*)(key + (long)bid * 32 * KEYD + 1024 + t * 4);

    const int lane = t & 63, wave = t >> 6;
    const int m = lane & 31, h = lane >> 5;
    float kreg[32];  // this lane's half of mode m's key row
    {
      const float* kmp = keys_map + m * KEYD + h * 32;
      #pragma unroll
      for (int j = 0; j < 32; j += 4) {
        const float4 v = *(const float4*)(kmp + j);
        kreg[j] = v.x; kreg[j + 1] = v.y; kreg[j + 2] = v.z; kreg[j + 3] = v.w;
      }
    }
    const float sv = sens[m];
    __syncthreads();

    #pragma unroll
    for (int rr = 0; rr < 8; ++rr) {
      const int rl = wave * 8 + rr;
      const long row = (long)bid * 32 + rl;

      float d2h = 0.f;
      #pragma unroll
      for (int j = 0; j < 32; j += 2) {
        const float2 kv = *(const float2*)(&kr[rl][h * 32 + j]);
        float a = kv.x - kreg[j], b = kv.y - kreg[j + 1];
        d2h += a * a + b * b;
      }
      float d2 = d2h + __shfl_xor(d2h, 32, 64);
      float logit = sv / (sqrtf(d2) + 1.0f);
      float mx = logit;
      #pragma unroll
      for (int off = 16; off > 0; off >>= 1) mx = fmaxf(mx, __shfl_xor(mx, off, 64));
      float e = __expf(logit - mx);
      float s = e;
      #pragma unroll
      for (int off = 16; off > 0; off >>= 1) s += __shfl_xor(s, off, 64);
      if (h == 0) sim[row * MODES + m] = e / s;

      const float2 xv = *(const float2*)(x + row * DDIM + lane * 2);
      ushort2 o; o.x = f2bf(xv.x); o.y = f2bf(xv.y);
      *(ushort2*)(x16 + row * DDIM + lane * 2) = o;
    }
  } else {
    int tt = (bid - BATCH / 32) * 256 + t;
    if (tt < MODES * 16 * UDIM) {
      int u = tt & 127, kb = (tt >> 7) & 15, m = tt >> 11;
      const float* src = kernels + (long)((m * 16 + kb) * 8) * UDIM + u;
      ushort4 lo, hi;
      lo.x = f2bf(src[0 * UDIM]); lo.y = f2bf(src[1 * UDIM]);
      lo.z = f2bf(src[2 * UDIM]); lo.w = f2bf(src[3 * UDIM]);
      hi.x = f2bf(src[4 * UDIM]); hi.y = f2bf(src[5 * UDIM]);
      hi.z = f2bf(src[6 * UDIM]); hi.w = f2bf(src[7 * UDIM]);
      *(ushort4*)(kb16 + (long)tt * 8) = lo;
      *(ushort4*)(kb16 + (long)tt * 8 + 4) = hi;
    } else {
      int tb = tt - MODES * 16 * UDIM;
      int u = tb & 127, kb = tb >> 7;
      const float* src = biases + kb * 8 * UDIM + u;
      ushort4 lo, hi;
      lo.x = f2bf(src[0 * UDIM]); lo.y = f2bf(src[1 * UDIM]);
      lo.z = f2bf(src[2 * UDIM]); lo.w = f2bf(src[3 * UDIM]);
      hi.x = f2bf(src[4 * UDIM]); hi.y = f2bf(src[5 * UDIM]);
      hi.z = f2bf(src[6 * UDIM]); hi.w = f2bf(src[7 * UDIM]);
      *(ushort4*)(bb16 + (long)tb * 8) = lo;
      *(ushort4*)(bb16 + (long)tb * 8 + 4) = hi;
    }
  }
}

// ---------------------------------------------------------------------------
// Barrier-free per-wave-pipelined GEMM over all 32 modes.
//   Grid 512 blocks x 256 thr (4 waves), XCD-swizzled so the two column
//   halves of a row panel share an XCD. Block = 64 rows x 64 cols; wave =
//   64 rows x 16 cols. KEY FACT: each wave reads ONLY its own 16 B-columns,
//   so each wave stages its own 4 KB/mode into its own LDS ring (4 bufs,
//   16 KB) via global_load_lds — NO cross-wave dependency, NO __syncthreads
//   in the main loop, counted s_waitcnt vmcnt(8) (2 modes stay in flight).
//   Waves phase-shift naturally -> staging overlaps MFMA by construction.
//   LDS = 4x16KB + simT 8KB = 72 KB -> 2 blocks/CU.
// ---------------------------------------------------------------------------
#define MODE_STRIDE (16 * UDIM * 8)  // shorts per mode in kb16 (32 KB)

#define WAITV(n) asm volatile("s_waitcnt vmcnt(" #n ")" ::: "memory")

__global__ __launch_bounds__(256, 2) void gemm_fused(
    const unsigned short* __restrict__ x16, const unsigned short* __restrict__ kb16,
    const unsigned short* __restrict__ bb16, const float* __restrict__ sim,
    float* __restrict__ out) {
  __shared__ alignas(16) unsigned short bsh[4][4][2048];  // [wave][buf][4KB]
  __shared__ float simT[MODES][64];                       // 8 KB

  const int t = threadIdx.x;
  const int lane = t & 63, w = t >> 6;
  const int q = lane >> 4, l16 = lane & 15;

  // XCD-contiguous swizzle (512 blocks, 8 XCDs, bijective): logical id l;
  // pair (bx, ch=0/1) lands on the same XCD -> x16 panel read once per XCD.
  const int bid0 = blockIdx.x;
  const int lgc = (bid0 & 7) * 64 + (bid0 >> 3);
  const int bx = lgc >> 1, ch = lgc & 1;
  const long bm = (long)bx * 64;
  const int uc = w * 16 + l16;  // local col in this block's 64-col half

  // stage sim transposed: 64 rows x 32 modes; 256 thr x 8 floats, coalesced
  {
    const int r = t >> 2, mg = (t & 3) * 8;
    const float4 v0 = *(const float4*)(sim + (bm + r) * MODES + mg);
    const float4 v1 = *(const float4*)(sim + (bm + r) * MODES + mg + 4);
    simT[mg + 0][r] = v0.x; simT[mg + 1][r] = v0.y;
    simT[mg + 2][r] = v0.z; simT[mg + 3][r] = v0.w;
    simT[mg + 4][r] = v1.x; simT[mg + 5][r] = v1.y;
    simT[mg + 6][r] = v1.z; simT[mg + 7][r] = v1.w;
  }
  __syncthreads();  // the ONLY block-wide barrier

  // A fragments: full 64-row x K=128 tile in registers (64 VGPRs).
  // A[row = rt*16 + l16][k = ks*32 + q*8 + j]
  bf16x8 aF[4][4];
  #pragma unroll
  for (int rt = 0; rt < 4; ++rt)
    #pragma unroll
    for (int ks = 0; ks < 4; ++ks)
      aF[rt][ks] = *(const bf16x8*)(x16 + (bm + rt * 16 + l16) * DDIM + ks * 32 + q * 8);

  // per-lane global source offset (shorts) for this wave's 16 columns:
  // chunk j covers kb = j*4 + (lane>>4), u = ch*64 + w*16 + (lane&15)
  const int stg_g = ((lane >> 4) * UDIM + ch * 64 + w * 16 + (lane & 15)) * 8;

#define STAGE(m, p) do {                                                        \
    const unsigned short* sg = kb16 + (long)(m) * MODE_STRIDE + stg_g;          \
    _Pragma("unroll")                                                           \
    for (int j = 0; j < 4; ++j)                                                 \
      gld_lds16(sg + j * (4 * UDIM * 8), &bsh[w][p][(j * 64 + lane) * 8]);      \
  } while (0)

  // prologue: fill 3 of the 4 ring slots (12 DMA ops in flight per thread)
  STAGE(0, 0); STAGE(1, 1); STAGE(2, 2);

  f32x4 acc[4] = {};

  #pragma unroll
  for (int mi = 0; mi < MODES; ++mi) {
    // counted wait: mode mi's 4 DMAs done; up to 8 (modes mi+1, mi+2) remain
    if (mi < 30) WAITV(8);
    else if (mi == 30) WAITV(4);
    else WAITV(0);

    if (mi < MODES - 3) STAGE(mi + 3, (mi + 3) & 3);  // refill ring slot

    const unsigned short* bs = &bsh[w][mi & 3][0];
    bf16x8 bF[4];  // [ks]: fragment (kb=ks*4+q, u=l16), contiguous 16B
    #pragma unroll
    for (int ks = 0; ks < 4; ++ks)
      bF[ks] = *(const bf16x8*)&bs[((ks * 4 + q) * 16 + l16) * 8];

    f32x4 tmp[4] = {};
    #pragma unroll
    for (int ks = 0; ks < 4; ++ks)
      #pragma unroll
      for (int rt = 0; rt < 4; ++rt)
        tmp[rt] = __builtin_amdgcn_mfma_f32_16x16x32_bf16(aF[rt][ks], bF[ks], tmp[rt], 0, 0, 0);

    #pragma unroll
    for (int rt = 0; rt < 4; ++rt) {
      const f32x4 sv = *(const f32x4*)&simT[mi][rt * 16 + q * 4];
      acc[rt] += sv * tmp[rt];
    }
  }
#undef STAGE

  // bias term: one K=32 MFMA round (A = sim rows in bf16, B = biases)
  {
    const bf16x8 bb = *(const bf16x8*)(bb16 + ((long)q * UDIM + ch * 64 + uc) * 8);
    #pragma unroll
    for (int rt = 0; rt < 4; ++rt) {
      const float* sp = sim + (bm + rt * 16 + l16) * MODES + q * 8;
      const float4 sv0 = *(const float4*)(sp);
      const float4 sv1 = *(const float4*)(sp + 4);
      bf16x8 sF;
      sF[0] = (short)f2bf(sv0.x); sF[1] = (short)f2bf(sv0.y);
      sF[2] = (short)f2bf(sv0.z); sF[3] = (short)f2bf(sv0.w);
      sF[4] = (short)f2bf(sv1.x); sF[5] = (short)f2bf(sv1.y);
      sF[6] = (short)f2bf(sv1.z); sF[7] = (short)f2bf(sv1.w);
      acc[rt] = __builtin_amdgcn_mfma_f32_16x16x32_bf16(sF, bb, acc[rt], 0, 0, 0);
    }
  }

  // epilogue: direct store, 1/MODES folded in; each out element written once
  #pragma unroll
  for (int rt = 0; rt < 4; ++rt) {
    const long row = bm + rt * 16 + q * 4;
    #pragma unroll
    for (int r = 0; r < 4; ++r)
      out[(row + r) * UDIM + ch * 64 + uc] = acc[rt][r] * (1.0f / MODES);
  }
}

extern "C" void kernel_launch(void* const* d_in, const int* in_sizes, int n_in,
                              void* d_out, int out_size, void* d_ws, size_t ws_size,
                              hipStream_t stream) {
  const float* key      = (const float*)d_in[0];
  const float* x        = (const float*)d_in[1];
  const float* sens     = (const float*)d_in[2];
  const float* keys_map = (const float*)d_in[3];
  const float* kernels  = (const float*)d_in[4];
  const float* biases   = (const float*)d_in[5];
  float* out = (float*)d_out;

  char* ws = (char*)d_ws;
  float*          sim  = (float*)ws;                          // 2 MB
  unsigned short* x16  = (unsigned short*)(ws + (2u << 20));  // 4 MB
  unsigned short* kb16 = (unsigned short*)(ws + (6u << 20));  // 1 MB
  unsigned short* bb16 = (unsigned short*)(ws + (7u << 20));  // 8 KB

  prep_all<<<BATCH / 32 + 258, 256, 0, stream>>>(
      key, x, sens, keys_map, kernels, biases, sim, x16, kb16, bb16);
  gemm_fused<<<dim3(512), 256, 0, stream>>>(x16, kb16, bb16, sim, out);
}